// Round 10
// baseline (56.950 us; speedup 1.0000x reference)
//
#include <hip/hip_runtime.h>
#include <hip/hip_bf16.h>

typedef short short8 __attribute__((ext_vector_type(8)));
typedef float f32x4 __attribute__((ext_vector_type(4)));
typedef unsigned short u16;

// ---------------- workspace layout (bytes) ----------------
#define XT_OFF   0
#define XT_BYTES (2*78*78*512*2)                  // 12,460,032
#define WR2_OFF  (XT_OFF + XT_BYTES)
#define WR2_BYTES (2*9*16*8*64*16)                // 2,359,296
#define AFTER_W  (WR2_OFF + WR2_BYTES)            // 14,819,328
// --- partial-store path: P bf16 [cq4][u4][oc128][pos4096] ---
#define P_OFF    AFTER_W
#define P_BYTES  (4*4*128*4096*2)                 // 16,777,216
#define GA_OFF_P (P_OFF + P_BYTES)
// --- atomic fallback path ---
#define CA_OFF   AFTER_W
#define CA_BYTES (4*4096*128*4)
#define GA_OFF_A (CA_OFF + CA_BYTES)
// tail (relative to GA_OFF_x): gapacc | gv | zv
#define GA_BYTES 2048
#define GV_REL   GA_BYTES
#define ZV_REL   (GV_REL + 4*512*4)
#define TAIL_END (ZV_REL + 4*256*4)
#define WS_NEED_P ((size_t)GA_OFF_P + TAIL_END)
#define WS_NEED_A ((size_t)GA_OFF_A + TAIL_END)

static __device__ __forceinline__ void async_cp16(u16* lds, const u16* g) {
  __builtin_amdgcn_global_load_lds(
      (const __attribute__((address_space(1))) void*)g,
      (__attribute__((address_space(3))) void*)lds, 16, 0, 0);
}

// ---------------- zero fill (fallback path only) ----------------
__global__ void zero_u4(uint4* __restrict__ p, int n) {
  int i = blockIdx.x * blockDim.x + threadIdx.x;
  int st = gridDim.x * blockDim.x;
  uint4 z = {0u, 0u, 0u, 0u};
  for (; i < n; i += st) p[i] = z;
}

// ---------------- prep_all: prep_x (0..1023) | halo zero | W pack ----------------
__global__ void prep_all(const float* __restrict__ x, u16* __restrict__ xT,
                         const float* __restrict__ W2, const float* __restrict__ W4,
                         u16* __restrict__ Wr2) {
  int bid = blockIdx.x;
  int t = threadIdx.x;
  if (bid < 1024) {
    // x -> xTpad (fp32 NCHW -> bf16 [b][h+7][w+7][c])
    __shared__ float tile[64][65];
    int bh = bid >> 3, cc = bid & 7;
    int b = bh >> 6, h = bh & 63;
    int w = t & 63, cq4 = t >> 6;
    int pi = t >> 2, q = t & 3;
#pragma unroll
    for (int i = 0; i < 16; ++i) {
      int ci = cq4 + i * 4;
      tile[ci][w] = x[((b * 512 + cc * 64 + ci) * 4096) + h * 64 + w];
    }
    __syncthreads();
    union { u16 u[16]; uint4 v[2]; } pk;
#pragma unroll
    for (int k = 0; k < 16; ++k) {
      __hip_bfloat16 hb = __float2bfloat16(tile[q * 16 + k][pi]);
      pk.u[k] = *(u16*)&hb;
    }
    u16* dst = xT + ((size_t)(b * 78 + h + 7) * 78 + (pi + 7)) * 512 + cc * 64 + q * 16;
    *(uint4*)dst = pk.v[0];
    *(uint4*)(dst + 8) = pk.v[1];
  } else if (bid < 1312) {
    // zero the halo of xTpad
    int hb = bid - 1024;
    size_t off; int cnt;
    if (hb < 256) {  // w-strips: h in [7,71), w in [0,7) or [71,78)
      int b = hb >> 7, rem = hb & 127, h = rem >> 1, side = rem & 1;
      off = ((size_t)(b * 78 + 7 + h) * 78 + (side ? 71 : 0)) * 512;
      cnt = 7 * 512;
    } else {          // h-spans: rows [0,7) and [71,78)
      int k = hb - 256;
      int b = k >> 4, topbot = (k >> 3) & 1, ch = k & 7;
      off = ((size_t)b * 78 + (topbot ? 71 : 0)) * 78 * 512 + (size_t)ch * 34944;
      cnt = 34944;
    }
    uint4* p = (uint4*)(xT + off);
    int n = cnt >> 3;
    uint4 z = {0u, 0u, 0u, 0u};
    for (int i = t; i < n; i += blockDim.x) p[i] = z;
  } else {
    // coalesced W pack: one block per (conv, oc)
    int idx = bid - 1312;
    int conv = idx >> 7, o = idx & 127;
    const float* W = conv ? W4 : W2;
    __shared__ float sw[4608];
    const float* src = W + (size_t)o * 4608;
    for (int k = 0; k < 18; ++k) sw[t + k * 256] = src[t + k * 256];
    __syncthreads();
    if (t < 144) {
      int tap = t >> 4, kc = t & 15;
      int wn = o >> 6, ni = (o >> 4) & 3;
      size_t base = (size_t)conv * 589824 + (size_t)(tap * 16 + kc) * 4096
                    + (wn * 4 + ni) * 512;
#pragma unroll
      for (int cg = 0; cg < 4; ++cg) {
        union { u16 h[8]; uint4 v; } pk;
#pragma unroll
        for (int e = 0; e < 8; ++e) {
          __hip_bfloat16 hb = __float2bfloat16(sw[(kc * 32 + cg * 8 + e) * 9 + tap]);
          pk.h[e] = *(u16*)&hb;
        }
        int lane = cg * 16 + (o & 15);
        *(uint4*)(Wr2 + base + lane * 8) = pk.v;
      }
    }
  }
}

// ---------------- dilated conv via MFMA, BK=64, wave-tile 128pos x 32oc ----------------
// decode: bid = [b:1][pthi:2][conv:1][cq:2][xcd:3]
// Each wave wv owns oc slice [wv*32,+32) over ALL 128 pos; A via global_load_lds
// (swizzled source, linear LDS); counted vmcnt at barriers.
// MODE 0 epilogue: P[cq][u][oc][pos] with jj-packed 8B stores (4x fewer VMEM ops).
template<int MODE>
__global__ __launch_bounds__(256, 2) void conv_mfma(
    const u16* __restrict__ xT, const u16* __restrict__ Wr2,
    u16* __restrict__ Pp, float* __restrict__ convacc) {
  __shared__ __align__(16) u16 Ab[2][8192];     // 2 x 16KB
  int bid = blockIdx.x;
  int xcd = bid & 7, cq = (bid >> 3) & 3, conv = (bid >> 5) & 1;
  int pthi = (bid >> 6) & 3, b = bid >> 8;
  int pt = pthi * 8 + xcd;
  int u = conv * 2 + b;
  int d = conv ? 7 : 3;
  int h0 = pt * 2;
  const u16* xb = xT + (size_t)b * (78 * 78 * 512);
  int t = threadIdx.x, l = t & 63, wv = t >> 6;   // wv = oc-slice index

  int slog = (l & 7) ^ (l >> 3);
  int wq = wv * 8 + (l >> 3);                    // w within half
  const u16* gA[4];
#pragma unroll
  for (int m = 0; m < 4; ++m) {
    int hh = m >> 1, mh = m & 1;
    gA[m] = xb + ((size_t)(h0 + hh - d + 7) * 78 + (mh * 32 + wq - d + 7)) * 512
            + cq * 128 + slog * 8;
  }
  // B: frag rows {2wv, 2wv+1} of the 8 oc16-rows per kc
  const char* bB = (const char*)Wr2 + (size_t)conv * 1179648
                   + cq * 32768 + wv * 2048 + l * 16;

  int rbase = (l & 15) * 64;
  int rs0 = (((l >> 4)) ^ (l & 7)) * 8;
  int rs1 = ((4 + (l >> 4)) ^ (l & 7)) * 8;

  f32x4 acc[8][2];   // [mi][ni]
#pragma unroll
  for (int i = 0; i < 8; ++i)
#pragma unroll
    for (int jj = 0; jj < 2; ++jj) acc[i][jj] = (f32x4){0.f, 0.f, 0.f, 0.f};

  short8 bf0[2][2], bf1[2][2];   // [c01][ni]

  auto issueA = [&](int buf) {
#pragma unroll
    for (int m = 0; m < 4; ++m)
      async_cp16(&Ab[buf][m * 2048 + wv * 512], gA[m]);
    __builtin_amdgcn_sched_barrier(0);   // pin: cp16s issue before the B loads
  };
  auto loadB = [&](short8 bf[2][2]) {
#pragma unroll
    for (int c01 = 0; c01 < 2; ++c01)
#pragma unroll
      for (int ni = 0; ni < 2; ++ni)
        bf[c01][ni] = *(const short8*)(bB + c01 * 8192 + ni * 1024);
  };
  auto cbar = [&]() {
    __builtin_amdgcn_sched_barrier(0);
    asm volatile("s_waitcnt vmcnt(4)" ::: "memory");   // drain the 4 cp16s, B regs fly on
    __builtin_amdgcn_s_barrier();
    __builtin_amdgcn_sched_barrier(0);
  };
  auto advance = [&](int s) {     // pointers: step s -> s+1
    int dA, dB;
    if (!(s & 1)) { dA = 64; dB = 16384; }       // u16 / bytes
    else {
      dB = 114688;
      int tap = (s + 1) >> 1;
      dA = (tap % 3) ? (512 * d - 64) : (38912 * d - 64);   // u16
    }
#pragma unroll
    for (int m = 0; m < 4; ++m) gA[m] += dA;
    bB += dB;
  };
  auto compute = [&](int buf, short8 bf[2][2]) {
    const u16* A = Ab[buf];
#pragma unroll
    for (int mi = 0; mi < 8; ++mi) {
      short8 a0 = *(const short8*)&A[rbase + mi * 1024 + rs0];
      short8 a1 = *(const short8*)&A[rbase + mi * 1024 + rs1];
      acc[mi][0] = __builtin_amdgcn_mfma_f32_16x16x32_bf16(a0, bf[0][0], acc[mi][0], 0, 0, 0);
      acc[mi][1] = __builtin_amdgcn_mfma_f32_16x16x32_bf16(a0, bf[0][1], acc[mi][1], 0, 0, 0);
      acc[mi][0] = __builtin_amdgcn_mfma_f32_16x16x32_bf16(a1, bf[1][0], acc[mi][0], 0, 0, 0);
      acc[mi][1] = __builtin_amdgcn_mfma_f32_16x16x32_bf16(a1, bf[1][1], acc[mi][1], 0, 0, 0);
    }
  };

  issueA(0); loadB(bf0); advance(0);
  cbar();
  for (int it = 0; it < 9; ++it) {
    int s = it * 2;
    issueA(1); loadB(bf1); advance(s + 1);
    compute(0, bf0);
    cbar();
    if (it < 8) { issueA(0); loadB(bf0); advance(s + 2); }
    compute(1, bf1);
    cbar();
  }

  if (MODE == 0) {
    // P[cq][u][oc][pos]: thread owns oc = wv*32 + ni*16 + (l&15),
    // pos = pt*128 + mi*16 + (l>>4)*4 + jj -> jj packs into one 8B store.
    u16* PPt = Pp + ((size_t)(cq * 4 + u) * 128 + wv * 32 + (l & 15)) * 4096
               + pt * 128 + (l >> 4) * 4;
#pragma unroll
    for (int mi = 0; mi < 8; ++mi)
#pragma unroll
      for (int ni = 0; ni < 2; ++ni) {
        __hip_bfloat16 h0 = __float2bfloat16(acc[mi][ni][0]);
        __hip_bfloat16 h1 = __float2bfloat16(acc[mi][ni][1]);
        __hip_bfloat16 h2 = __float2bfloat16(acc[mi][ni][2]);
        __hip_bfloat16 h3 = __float2bfloat16(acc[mi][ni][3]);
        uint2 v;
        v.x = (unsigned)*(u16*)&h0 | ((unsigned)*(u16*)&h1 << 16);
        v.y = (unsigned)*(u16*)&h2 | ((unsigned)*(u16*)&h3 << 16);
        *(uint2*)(PPt + (size_t)ni * 65536 + mi * 16) = v;
      }
  } else {
    float* ca = convacc + (size_t)u * 4096 * 128;
#pragma unroll
    for (int mi = 0; mi < 8; ++mi)
#pragma unroll
      for (int ni = 0; ni < 2; ++ni)
#pragma unroll
        for (int jj = 0; jj < 4; ++jj) {
          int pos = pt * 128 + mi * 16 + (l >> 4) * 4 + jj;
          int oc = wv * 32 + ni * 16 + (l & 15);
          atomicAdd(&ca[pos * 128 + oc], acc[mi][ni][jj]);
        }
  }
}

// ---------------- bias + relu + GAP (partial path, transposed P) ----------------
// grid 512 = [u:4][oc:128]; block owns one (u,oc): 4096 pos x 4 cq, fully coalesced
// 8KB row reads; plain store to gapacc (no atomics, no pre-zero).
__global__ void reduce_gap_p(const u16* __restrict__ P,
                             const float* __restrict__ b2, const float* __restrict__ b4,
                             float* __restrict__ gapacc) {
  int u = blockIdx.x >> 7, oc = blockIdx.x & 127;
  const float* bias = (u >> 1) ? b4 : b2;
  int t = threadIdx.x;
  float bi = bias[oc];
  const u16* p0 = P + ((size_t)u * 128 + oc) * 4096 + t * 16;
  float v[16];
#pragma unroll
  for (int k = 0; k < 16; ++k) v[k] = bi;
#pragma unroll
  for (int cq = 0; cq < 4; ++cq) {
    const u16* pp = p0 + (size_t)cq * 2097152;
    uint4 a = *(const uint4*)pp;
    uint4 bq = *(const uint4*)(pp + 8);
    unsigned w[8] = {a.x, a.y, a.z, a.w, bq.x, bq.y, bq.z, bq.w};
#pragma unroll
    for (int k = 0; k < 8; ++k) {
      v[2 * k]     += __builtin_bit_cast(float, (w[k] & 0xffffu) << 16);
      v[2 * k + 1] += __builtin_bit_cast(float, w[k] & 0xffff0000u);
    }
  }
  float s = 0.f;
#pragma unroll
  for (int k = 0; k < 16; ++k) s += v[k] > 0.f ? v[k] : 0.f;
#pragma unroll
  for (int m = 1; m < 64; m <<= 1) s += __shfl_xor(s, m);
  __shared__ float red[4];
  if ((t & 63) == 0) red[t >> 6] = s;
  __syncthreads();
  if (t == 0) gapacc[u * 128 + oc] = red[0] + red[1] + red[2] + red[3];
}

// ---------------- bias + relu + GAP (atomic fallback path) ----------------
__global__ void reduce_gap_a(const float* __restrict__ convacc,
                             const float* __restrict__ b2, const float* __restrict__ b4,
                             float* __restrict__ gapacc) {
  int unit = blockIdx.x >> 5, chunk = blockIdx.x & 31;
  int conv = unit >> 1;
  const float* bias = conv ? b4 : b2;
  int t = threadIdx.x, oc = t & 127, half = t >> 7;
  const float* ca = convacc + (size_t)unit * 4096 * 128;
  float bi = bias[oc];
  float s = 0.f;
  for (int i = 0; i < 64; ++i) {
    int pos = chunk * 128 + half * 64 + i;
    float v = ca[pos * 128 + oc] + bi;
    s += v > 0.f ? v : 0.f;
  }
  __shared__ float red[2][128];
  red[half][oc] = s;
  __syncthreads();
  if (t < 128) atomicAdd(&gapacc[unit * 128 + t], red[0][t] + red[1][t]);
}

// ---------------- dense chain, stage 1: gv[combo][o] = Wd[o,:].gap[combo] ----------------
__global__ void dense1(const float* __restrict__ gapacc, const float* __restrict__ Wd,
                       float* __restrict__ gv) {
  int o = blockIdx.x, t = threadIdx.x;
  float w = Wd[o * 128 + t];
  float p0 = w * gapacc[2 * 128 + t];
  float p1 = w * gapacc[0 * 128 + t];
  float p2 = w * gapacc[3 * 128 + t];
  float p3 = w * gapacc[1 * 128 + t];
#pragma unroll
  for (int m = 1; m < 64; m <<= 1) {
    p0 += __shfl_xor(p0, m); p1 += __shfl_xor(p1, m);
    p2 += __shfl_xor(p2, m); p3 += __shfl_xor(p3, m);
  }
  __shared__ float red[2][4];
  if ((t & 63) == 0) {
    red[t >> 6][0] = p0; red[t >> 6][1] = p1;
    red[t >> 6][2] = p2; red[t >> 6][3] = p3;
  }
  __syncthreads();
  if (t < 4) {
    const float inv = 1.f / 4096.f;
    gv[t * 512 + o] = (red[0][t] + red[1][t]) * inv;
  }
}

// ---------------- stage 2: zv[combo][o] = bcc[o] + Wcc[o,:].gv[combo] ----------------
__global__ void dense2(const float* __restrict__ gv, const float* __restrict__ Wcc,
                       const float* __restrict__ bcc, float* __restrict__ zv) {
  int o = blockIdx.x, t = threadIdx.x;
  float w0 = Wcc[o * 512 + t], w1 = Wcc[o * 512 + 256 + t];
  float p[4];
#pragma unroll
  for (int c = 0; c < 4; ++c)
    p[c] = w0 * gv[c * 512 + t] + w1 * gv[c * 512 + 256 + t];
#pragma unroll
  for (int m = 1; m < 64; m <<= 1)
#pragma unroll
    for (int c = 0; c < 4; ++c) p[c] += __shfl_xor(p[c], m);
  __shared__ float red[4][4];
  if ((t & 63) == 0)
#pragma unroll
    for (int c = 0; c < 4; ++c) red[t >> 6][c] = p[c];
  __syncthreads();
  if (t < 4) {
    float s = bcc[o];
#pragma unroll
    for (int wv = 0; wv < 4; ++wv) s += red[wv][t];
    zv[t * 256 + o] = s;
  }
}

// ---------------- out = x + cvec[b][ch], cvec computed in-block from zv (dense3 fused) ----
__global__ void final_add(const float* __restrict__ x, const float* __restrict__ zv,
                          const float* __restrict__ Wd2, float* __restrict__ out) {
  int t = threadIdx.x, bid = blockIdx.x;
  int ch = (bid >> 2) & 511;
  float w = Wd2[ch * 256 + t];
  float p0 = w * (zv[t] + zv[256 + t]);
  float p1 = w * (zv[512 + t] + zv[768 + t]);
#pragma unroll
  for (int m = 1; m < 64; m <<= 1) {
    p0 += __shfl_xor(p0, m);
    p1 += __shfl_xor(p1, m);
  }
  __shared__ float red[4][2];
  __shared__ float cv[2];
  if ((t & 63) == 0) { red[t >> 6][0] = p0; red[t >> 6][1] = p1; }
  __syncthreads();
  if (t < 2) cv[t] = red[0][t] + red[1][t] + red[2][t] + red[3][t];
  __syncthreads();
  const float4* x4 = (const float4*)x;
  float4* o4 = (float4*)out;
  int i = bid * 256 + t;
  float c0 = cv[0], c1 = cv[1];
  float4 v = x4[i];
  v.x += c0; v.y += c0; v.z += c0; v.w += c0;
  o4[i] = v;
  i += 524288;
  float4 v2 = x4[i];
  v2.x += c1; v2.y += c1; v2.z += c1; v2.w += c1;
  o4[i] = v2;
}

extern "C" void kernel_launch(void* const* d_in, const int* in_sizes, int n_in,
                              void* d_out, int out_size, void* d_ws, size_t ws_size,
                              hipStream_t stream) {
  const float* x   = (const float*)d_in[0];
  const float* W2  = (const float*)d_in[3];
  const float* b2  = (const float*)d_in[4];
  const float* W4  = (const float*)d_in[7];
  const float* b4  = (const float*)d_in[8];
  const float* Wd  = (const float*)d_in[9];
  const float* Wcc = (const float*)d_in[10];
  const float* bcc = (const float*)d_in[11];
  const float* Wd2 = (const float*)d_in[12];
  float* out = (float*)d_out;

  char* ws = (char*)d_ws;
  u16* xT  = (u16*)(ws + XT_OFF);
  u16* Wr2 = (u16*)(ws + WR2_OFF);

  const bool partial = ws_size >= WS_NEED_P;
  size_t ga_off = partial ? GA_OFF_P : GA_OFF_A;
  float* gapacc = (float*)(ws + ga_off);
  float* gv     = (float*)(ws + ga_off + GV_REL);
  float* zv     = (float*)(ws + ga_off + ZV_REL);

  prep_all<<<1568, 256, 0, stream>>>(x, xT, W2, W4, Wr2);

  if (partial) {
    u16* Pp = (u16*)(ws + P_OFF);
    conv_mfma<0><<<512, 256, 0, stream>>>(xT, Wr2, Pp, nullptr);
    reduce_gap_p<<<512, 256, 0, stream>>>(Pp, b2, b4, gapacc);
  } else {
    float* convacc = (float*)(ws + CA_OFF);
    // zero convacc AND gapacc (contiguous) — fallback path uses atomics into both
    zero_u4<<<512, 256, 0, stream>>>((uint4*)convacc, (CA_BYTES + GA_BYTES) / 16);
    conv_mfma<1><<<512, 256, 0, stream>>>(xT, Wr2, nullptr, convacc);
    reduce_gap_a<<<128, 256, 0, stream>>>(convacc, b2, b4, gapacc);
  }

  dense1<<<512, 128, 0, stream>>>(gapacc, Wd, gv);
  dense2<<<256, 256, 0, stream>>>(gv, Wcc, bcc, zv);
  final_add<<<2048, 256, 0, stream>>>(x, zv, Wd2, out);
}

// Round 13
// 53.662 us; speedup vs baseline: 1.0613x; 1.0613x over previous
//
#include <hip/hip_runtime.h>
#include <hip/hip_bf16.h>

typedef short short8 __attribute__((ext_vector_type(8)));
typedef float f32x4 __attribute__((ext_vector_type(4)));
typedef unsigned short u16;

// ---------------- workspace layout (bytes) ----------------
#define XT_OFF   0
#define XT_BYTES (2*78*78*512*2)                  // 12,460,032
#define WR2_OFF  (XT_OFF + XT_BYTES)
#define WR2_BYTES (2*9*16*8*64*16)                // 2,359,296
#define AFTER_W  (WR2_OFF + WR2_BYTES)            // 14,819,328
// --- partial-store path: P bf16 [cq4][u4][oc128][pos4096] ---
#define P_OFF    AFTER_W
#define P_BYTES  (4*4*128*4096*2)                 // 16,777,216
#define GA_OFF_P (P_OFF + P_BYTES)
// --- atomic fallback path ---
#define CA_OFF   AFTER_W
#define CA_BYTES (4*4096*128*4)
#define GA_OFF_A (CA_OFF + CA_BYTES)
// tail (relative to GA_OFF_x): gapacc | gv | zv
#define GA_BYTES 2048
#define GV_REL   GA_BYTES
#define ZV_REL   (GV_REL + 4*512*4)
#define TAIL_END (ZV_REL + 4*256*4)
#define WS_NEED_P ((size_t)GA_OFF_P + TAIL_END)
#define WS_NEED_A ((size_t)GA_OFF_A + TAIL_END)

static __device__ __forceinline__ void async_cp16(u16* lds, const u16* g) {
  __builtin_amdgcn_global_load_lds(
      (const __attribute__((address_space(1))) void*)g,
      (__attribute__((address_space(3))) void*)lds, 16, 0, 0);
}

// ---------------- zero fill (fallback path only) ----------------
__global__ void zero_u4(uint4* __restrict__ p, int n) {
  int i = blockIdx.x * blockDim.x + threadIdx.x;
  int st = gridDim.x * blockDim.x;
  uint4 z = {0u, 0u, 0u, 0u};
  for (; i < n; i += st) p[i] = z;
}

// ---------------- prep_all: prep_x (0..1023) | halo zero | W pack ----------------
__global__ void prep_all(const float* __restrict__ x, u16* __restrict__ xT,
                         const float* __restrict__ W2, const float* __restrict__ W4,
                         u16* __restrict__ Wr2) {
  int bid = blockIdx.x;
  int t = threadIdx.x;
  if (bid < 1024) {
    // x -> xTpad (fp32 NCHW -> bf16 [b][h+7][w+7][c])
    __shared__ float tile[64][65];
    int bh = bid >> 3, cc = bid & 7;
    int b = bh >> 6, h = bh & 63;
    int w = t & 63, cq4 = t >> 6;
    int pi = t >> 2, q = t & 3;
#pragma unroll
    for (int i = 0; i < 16; ++i) {
      int ci = cq4 + i * 4;
      tile[ci][w] = x[((b * 512 + cc * 64 + ci) * 4096) + h * 64 + w];
    }
    __syncthreads();
    union { u16 u[16]; uint4 v[2]; } pk;
#pragma unroll
    for (int k = 0; k < 16; ++k) {
      __hip_bfloat16 hb = __float2bfloat16(tile[q * 16 + k][pi]);
      pk.u[k] = *(u16*)&hb;
    }
    u16* dst = xT + ((size_t)(b * 78 + h + 7) * 78 + (pi + 7)) * 512 + cc * 64 + q * 16;
    *(uint4*)dst = pk.v[0];
    *(uint4*)(dst + 8) = pk.v[1];
  } else if (bid < 1312) {
    // zero the halo of xTpad
    int hb = bid - 1024;
    size_t off; int cnt;
    if (hb < 256) {  // w-strips: h in [7,71), w in [0,7) or [71,78)
      int b = hb >> 7, rem = hb & 127, h = rem >> 1, side = rem & 1;
      off = ((size_t)(b * 78 + 7 + h) * 78 + (side ? 71 : 0)) * 512;
      cnt = 7 * 512;
    } else {          // h-spans: rows [0,7) and [71,78)
      int k = hb - 256;
      int b = k >> 4, topbot = (k >> 3) & 1, ch = k & 7;
      off = ((size_t)b * 78 + (topbot ? 71 : 0)) * 78 * 512 + (size_t)ch * 34944;
      cnt = 34944;
    }
    uint4* p = (uint4*)(xT + off);
    int n = cnt >> 3;
    uint4 z = {0u, 0u, 0u, 0u};
    for (int i = t; i < n; i += blockDim.x) p[i] = z;
  } else {
    // coalesced W pack: one block per (conv, oc)
    int idx = bid - 1312;
    int conv = idx >> 7, o = idx & 127;
    const float* W = conv ? W4 : W2;
    __shared__ float sw[4608];
    const float* src = W + (size_t)o * 4608;
    for (int k = 0; k < 18; ++k) sw[t + k * 256] = src[t + k * 256];
    __syncthreads();
    if (t < 144) {
      int tap = t >> 4, kc = t & 15;
      int wn = o >> 6, ni = (o >> 4) & 3;
      size_t base = (size_t)conv * 589824 + (size_t)(tap * 16 + kc) * 4096
                    + (wn * 4 + ni) * 512;
#pragma unroll
      for (int cg = 0; cg < 4; ++cg) {
        union { u16 h[8]; uint4 v; } pk;
#pragma unroll
        for (int e = 0; e < 8; ++e) {
          __hip_bfloat16 hb = __float2bfloat16(sw[(kc * 32 + cg * 8 + e) * 9 + tap]);
          pk.h[e] = *(u16*)&hb;
        }
        int lane = cg * 16 + (o & 15);
        *(uint4*)(Wr2 + base + lane * 8) = pk.v;
      }
    }
  }
}

// ---------------- dilated conv via MFMA, BK=64, wave-tile 128pos x 32oc ----------------
// decode: bid = [b:1][pthi:2][conv:1][cq:2][xcd:3]
// MODE 0 epilogue: stage C-tile in LDS [oc][pos] with 8B-chunk XOR swizzle
// (physical_chunk = logical_chunk ^ ((row&15)<<1)), then coalesced 16B copies to
// P[cq][u][oc][pos] (4 x 256B segments per wave store instruction).
template<int MODE>
__global__ __launch_bounds__(256, 2) void conv_mfma(
    const u16* __restrict__ xT, const u16* __restrict__ Wr2,
    u16* __restrict__ Pp, float* __restrict__ convacc) {
  __shared__ __align__(16) u16 Ab[2][8192];     // 2 x 16KB (reused as 32KB C-tile in epilogue)
  int bid = blockIdx.x;
  int xcd = bid & 7, cq = (bid >> 3) & 3, conv = (bid >> 5) & 1;
  int pthi = (bid >> 6) & 3, b = bid >> 8;
  int pt = pthi * 8 + xcd;
  int u = conv * 2 + b;
  int d = conv ? 7 : 3;
  int h0 = pt * 2;
  const u16* xb = xT + (size_t)b * (78 * 78 * 512);
  int t = threadIdx.x, l = t & 63, wv = t >> 6;   // wv = oc-slice index

  int slog = (l & 7) ^ (l >> 3);
  int wq = wv * 8 + (l >> 3);                    // w within half
  const u16* gA[4];
#pragma unroll
  for (int m = 0; m < 4; ++m) {
    int hh = m >> 1, mh = m & 1;
    gA[m] = xb + ((size_t)(h0 + hh - d + 7) * 78 + (mh * 32 + wq - d + 7)) * 512
            + cq * 128 + slog * 8;
  }
  // B: frag rows {2wv, 2wv+1} of the 8 oc16-rows per kc
  const char* bB = (const char*)Wr2 + (size_t)conv * 1179648
                   + cq * 32768 + wv * 2048 + l * 16;

  int rbase = (l & 15) * 64;
  int rs0 = (((l >> 4)) ^ (l & 7)) * 8;
  int rs1 = ((4 + (l >> 4)) ^ (l & 7)) * 8;

  f32x4 acc[8][2];   // [mi][ni]
#pragma unroll
  for (int i = 0; i < 8; ++i)
#pragma unroll
    for (int jj = 0; jj < 2; ++jj) acc[i][jj] = (f32x4){0.f, 0.f, 0.f, 0.f};

  short8 bf0[2][2], bf1[2][2];   // [c01][ni]

  auto issueA = [&](int buf) {
#pragma unroll
    for (int m = 0; m < 4; ++m)
      async_cp16(&Ab[buf][m * 2048 + wv * 512], gA[m]);
    __builtin_amdgcn_sched_barrier(0);   // pin: cp16s issue before the B loads
  };
  auto loadB = [&](short8 bf[2][2]) {
#pragma unroll
    for (int c01 = 0; c01 < 2; ++c01)
#pragma unroll
      for (int ni = 0; ni < 2; ++ni)
        bf[c01][ni] = *(const short8*)(bB + c01 * 8192 + ni * 1024);
  };
  auto cbar = [&]() {
    __builtin_amdgcn_sched_barrier(0);
    asm volatile("s_waitcnt vmcnt(4)" ::: "memory");   // drain the 4 cp16s, B regs fly on
    __builtin_amdgcn_s_barrier();
    __builtin_amdgcn_sched_barrier(0);
  };
  auto advance = [&](int s) {     // pointers: step s -> s+1
    int dA, dB;
    if (!(s & 1)) { dA = 64; dB = 16384; }       // u16 / bytes
    else {
      dB = 114688;
      int tap = (s + 1) >> 1;
      dA = (tap % 3) ? (512 * d - 64) : (38912 * d - 64);   // u16
    }
#pragma unroll
    for (int m = 0; m < 4; ++m) gA[m] += dA;
    bB += dB;
  };
  auto compute = [&](int buf, short8 bf[2][2]) {
    const u16* A = Ab[buf];
#pragma unroll
    for (int mi = 0; mi < 8; ++mi) {
      short8 a0 = *(const short8*)&A[rbase + mi * 1024 + rs0];
      short8 a1 = *(const short8*)&A[rbase + mi * 1024 + rs1];
      acc[mi][0] = __builtin_amdgcn_mfma_f32_16x16x32_bf16(a0, bf[0][0], acc[mi][0], 0, 0, 0);
      acc[mi][1] = __builtin_amdgcn_mfma_f32_16x16x32_bf16(a0, bf[0][1], acc[mi][1], 0, 0, 0);
      acc[mi][0] = __builtin_amdgcn_mfma_f32_16x16x32_bf16(a1, bf[1][0], acc[mi][0], 0, 0, 0);
      acc[mi][1] = __builtin_amdgcn_mfma_f32_16x16x32_bf16(a1, bf[1][1], acc[mi][1], 0, 0, 0);
    }
  };

  issueA(0); loadB(bf0); advance(0);
  cbar();
  for (int it = 0; it < 9; ++it) {
    int s = it * 2;
    issueA(1); loadB(bf1); advance(s + 1);
    compute(0, bf0);
    cbar();
    if (it < 8) { issueA(0); loadB(bf0); advance(s + 2); }
    compute(1, bf1);
    cbar();
  }

  if (MODE == 0) {
    // --- stage C-tile in LDS [oc 128][pos 128] bf16 (256B rows, 32 x 8B chunks) ---
    // writer: logical chunk = mi*4 + (l>>4), physical = chunk ^ ((oc&15)<<1)
    // (oc&15 == l&15). Write aliasing is <=4-way (cheap, once per block).
    u16* L = (u16*)Ab;   // 32KB flat; main loop done (last cbar barriered)
#pragma unroll
    for (int mi = 0; mi < 8; ++mi)
#pragma unroll
      for (int ni = 0; ni < 2; ++ni) {
        int oc = wv * 32 + ni * 16 + (l & 15);
        int chunk = mi * 4 + (l >> 4);
        int chs = chunk ^ ((l & 15) << 1);
        __hip_bfloat16 h0 = __float2bfloat16(acc[mi][ni][0]);
        __hip_bfloat16 h1 = __float2bfloat16(acc[mi][ni][1]);
        __hip_bfloat16 h2 = __float2bfloat16(acc[mi][ni][2]);
        __hip_bfloat16 h3 = __float2bfloat16(acc[mi][ni][3]);
        uint2 v;
        v.x = (unsigned)*(u16*)&h0 | ((unsigned)*(u16*)&h1 << 16);
        v.y = (unsigned)*(u16*)&h2 | ((unsigned)*(u16*)&h3 << 16);
        *(uint2*)&L[oc * 128 + chs * 4] = v;
      }
    __syncthreads();
    // --- coalesced copy LDS -> P[cq][u][oc][pos]: 8 x uint4 per thread ---
    // row r = 0..127 (256B each = 16 x 16B); 16B unit ci holds logical 8B chunks
    // {2ci, 2ci+1}; XOR key is even so both live adjacent at physical (2ci)^key.
    size_t gbase = (size_t)(cq * 4 + u) * 128 * 4096 + pt * 128;
#pragma unroll
    for (int k = 0; k < 8; ++k) {
      int C = t + k * 256;               // 16B unit id, 0..2047
      int r = C >> 4, ci = C & 15;
      int ch0 = (2 * ci) ^ ((r & 15) << 1);
      uint4 vv = *(const uint4*)&L[r * 128 + ch0 * 4];
      *(uint4*)(Pp + gbase + (size_t)r * 4096 + ci * 8) = vv;
    }
  } else {
    float* ca = convacc + (size_t)u * 4096 * 128;
#pragma unroll
    for (int mi = 0; mi < 8; ++mi)
#pragma unroll
      for (int ni = 0; ni < 2; ++ni)
#pragma unroll
        for (int jj = 0; jj < 4; ++jj) {
          int pos = pt * 128 + mi * 16 + (l >> 4) * 4 + jj;
          int oc = wv * 32 + ni * 16 + (l & 15);
          atomicAdd(&ca[pos * 128 + oc], acc[mi][ni][jj]);
        }
  }
}

// ---------------- bias + relu + GAP (partial path, pos-major P rows) ----------------
// grid 512 = [u:4][oc:128]; block owns one (u,oc): 4096 pos x 4 cq, fully coalesced
// 8KB row reads; plain store to gapacc (no atomics, no pre-zero).
__global__ void reduce_gap_p(const u16* __restrict__ P,
                             const float* __restrict__ b2, const float* __restrict__ b4,
                             float* __restrict__ gapacc) {
  int u = blockIdx.x >> 7, oc = blockIdx.x & 127;
  const float* bias = (u >> 1) ? b4 : b2;
  int t = threadIdx.x;
  float bi = bias[oc];
  const u16* p0 = P + ((size_t)u * 128 + oc) * 4096 + t * 16;
  float v[16];
#pragma unroll
  for (int k = 0; k < 16; ++k) v[k] = bi;
#pragma unroll
  for (int cq = 0; cq < 4; ++cq) {
    const u16* pp = p0 + (size_t)cq * 2097152;
    uint4 a = *(const uint4*)pp;
    uint4 bq = *(const uint4*)(pp + 8);
    unsigned w[8] = {a.x, a.y, a.z, a.w, bq.x, bq.y, bq.z, bq.w};
#pragma unroll
    for (int k = 0; k < 8; ++k) {
      v[2 * k]     += __builtin_bit_cast(float, (w[k] & 0xffffu) << 16);
      v[2 * k + 1] += __builtin_bit_cast(float, w[k] & 0xffff0000u);
    }
  }
  float s = 0.f;
#pragma unroll
  for (int k = 0; k < 16; ++k) s += v[k] > 0.f ? v[k] : 0.f;
#pragma unroll
  for (int m = 1; m < 64; m <<= 1) s += __shfl_xor(s, m);
  __shared__ float red[4];
  if ((t & 63) == 0) red[t >> 6] = s;
  __syncthreads();
  if (t == 0) gapacc[u * 128 + oc] = red[0] + red[1] + red[2] + red[3];
}

// ---------------- bias + relu + GAP (atomic fallback path) ----------------
__global__ void reduce_gap_a(const float* __restrict__ convacc,
                             const float* __restrict__ b2, const float* __restrict__ b4,
                             float* __restrict__ gapacc) {
  int unit = blockIdx.x >> 5, chunk = blockIdx.x & 31;
  int conv = unit >> 1;
  const float* bias = conv ? b4 : b2;
  int t = threadIdx.x, oc = t & 127, half = t >> 7;
  const float* ca = convacc + (size_t)unit * 4096 * 128;
  float bi = bias[oc];
  float s = 0.f;
  for (int i = 0; i < 64; ++i) {
    int pos = chunk * 128 + half * 64 + i;
    float v = ca[pos * 128 + oc] + bi;
    s += v > 0.f ? v : 0.f;
  }
  __shared__ float red[2][128];
  red[half][oc] = s;
  __syncthreads();
  if (t < 128) atomicAdd(&gapacc[unit * 128 + t], red[0][t] + red[1][t]);
}

// ---------------- dense chain, stage 1: gv[combo][o] = Wd[o,:].gap[combo] ----------------
__global__ void dense1(const float* __restrict__ gapacc, const float* __restrict__ Wd,
                       float* __restrict__ gv) {
  int o = blockIdx.x, t = threadIdx.x;
  float w = Wd[o * 128 + t];
  float p0 = w * gapacc[2 * 128 + t];
  float p1 = w * gapacc[0 * 128 + t];
  float p2 = w * gapacc[3 * 128 + t];
  float p3 = w * gapacc[1 * 128 + t];
#pragma unroll
  for (int m = 1; m < 64; m <<= 1) {
    p0 += __shfl_xor(p0, m); p1 += __shfl_xor(p1, m);
    p2 += __shfl_xor(p2, m); p3 += __shfl_xor(p3, m);
  }
  __shared__ float red[2][4];
  if ((t & 63) == 0) {
    red[t >> 6][0] = p0; red[t >> 6][1] = p1;
    red[t >> 6][2] = p2; red[t >> 6][3] = p3;
  }
  __syncthreads();
  if (t < 4) {
    const float inv = 1.f / 4096.f;
    gv[t * 512 + o] = (red[0][t] + red[1][t]) * inv;
  }
}

// ---------------- stage 2: zv[combo][o] = bcc[o] + Wcc[o,:].gv[combo] ----------------
__global__ void dense2(const float* __restrict__ gv, const float* __restrict__ Wcc,
                       const float* __restrict__ bcc, float* __restrict__ zv) {
  int o = blockIdx.x, t = threadIdx.x;
  float w0 = Wcc[o * 512 + t], w1 = Wcc[o * 512 + 256 + t];
  float p[4];
#pragma unroll
  for (int c = 0; c < 4; ++c)
    p[c] = w0 * gv[c * 512 + t] + w1 * gv[c * 512 + 256 + t];
#pragma unroll
  for (int m = 1; m < 64; m <<= 1)
#pragma unroll
    for (int c = 0; c < 4; ++c) p[c] += __shfl_xor(p[c], m);
  __shared__ float red[4][4];
  if ((t & 63) == 0)
#pragma unroll
    for (int c = 0; c < 4; ++c) red[t >> 6][c] = p[c];
  __syncthreads();
  if (t < 4) {
    float s = bcc[o];
#pragma unroll
    for (int wv = 0; wv < 4; ++wv) s += red[wv][t];
    zv[t * 256 + o] = s;
  }
}

// ---------------- out = x + cvec[b][ch], cvec computed in-block from zv (dense3 fused) ----
__global__ void final_add(const float* __restrict__ x, const float* __restrict__ zv,
                          const float* __restrict__ Wd2, float* __restrict__ out) {
  int t = threadIdx.x, bid = blockIdx.x;
  int ch = (bid >> 2) & 511;
  float w = Wd2[ch * 256 + t];
  float p0 = w * (zv[t] + zv[256 + t]);
  float p1 = w * (zv[512 + t] + zv[768 + t]);
#pragma unroll
  for (int m = 1; m < 64; m <<= 1) {
    p0 += __shfl_xor(p0, m);
    p1 += __shfl_xor(p1, m);
  }
  __shared__ float red[4][2];
  __shared__ float cv[2];
  if ((t & 63) == 0) { red[t >> 6][0] = p0; red[t >> 6][1] = p1; }
  __syncthreads();
  if (t < 2) cv[t] = red[0][t] + red[1][t] + red[2][t] + red[3][t];
  __syncthreads();
  const float4* x4 = (const float4*)x;
  float4* o4 = (float4*)out;
  int i = bid * 256 + t;
  float c0 = cv[0], c1 = cv[1];
  float4 v = x4[i];
  v.x += c0; v.y += c0; v.z += c0; v.w += c0;
  o4[i] = v;
  i += 524288;
  float4 v2 = x4[i];
  v2.x += c1; v2.y += c1; v2.z += c1; v2.w += c1;
  o4[i] = v2;
}

extern "C" void kernel_launch(void* const* d_in, const int* in_sizes, int n_in,
                              void* d_out, int out_size, void* d_ws, size_t ws_size,
                              hipStream_t stream) {
  const float* x   = (const float*)d_in[0];
  const float* W2  = (const float*)d_in[3];
  const float* b2  = (const float*)d_in[4];
  const float* W4  = (const float*)d_in[7];
  const float* b4  = (const float*)d_in[8];
  const float* Wd  = (const float*)d_in[9];
  const float* Wcc = (const float*)d_in[10];
  const float* bcc = (const float*)d_in[11];
  const float* Wd2 = (const float*)d_in[12];
  float* out = (float*)d_out;

  char* ws = (char*)d_ws;
  u16* xT  = (u16*)(ws + XT_OFF);
  u16* Wr2 = (u16*)(ws + WR2_OFF);

  const bool partial = ws_size >= WS_NEED_P;
  size_t ga_off = partial ? GA_OFF_P : GA_OFF_A;
  float* gapacc = (float*)(ws + ga_off);
  float* gv     = (float*)(ws + ga_off + GV_REL);
  float* zv     = (float*)(ws + ga_off + ZV_REL);

  prep_all<<<1568, 256, 0, stream>>>(x, xT, W2, W4, Wr2);

  if (partial) {
    u16* Pp = (u16*)(ws + P_OFF);
    conv_mfma<0><<<512, 256, 0, stream>>>(xT, Wr2, Pp, nullptr);
    reduce_gap_p<<<512, 256, 0, stream>>>(Pp, b2, b4, gapacc);
  } else {
    float* convacc = (float*)(ws + CA_OFF);
    // zero convacc AND gapacc (contiguous) — fallback path uses atomics into both
    zero_u4<<<512, 256, 0, stream>>>((uint4*)convacc, (CA_BYTES + GA_BYTES) / 16);
    conv_mfma<1><<<512, 256, 0, stream>>>(xT, Wr2, nullptr, convacc);
    reduce_gap_a<<<128, 256, 0, stream>>>(convacc, b2, b4, gapacc);
  }

  dense1<<<512, 128, 0, stream>>>(gapacc, Wd, gv);
  dense2<<<256, 256, 0, stream>>>(gv, Wcc, bcc, zv);
  final_add<<<2048, 256, 0, stream>>>(x, zv, Wd2, out);
}